// Round 8
// baseline (247.909 us; speedup 1.0000x reference)
//
#include <hip/hip_runtime.h>
#include <hip/hip_bf16.h>
#include <stdint.h>

// Problem constants
#define B_    8
#define CIN   128
#define H_    64
#define W_    64
#define COUT  128
#define K_    16
#define HO    61
#define WO    61
#define HW_   (HO * WO)          // 3721
#define KKTOT (CIN * K_)         // 2048
#define KKQ   512                // kk' per quarter (Bs = 16 KB)
#define TILW  33                 // tile row stride in 16B words (pad +1)
#define TILWDS (16 * TILW)       // 528 words/buffer = 8448 B

typedef short bf16x8 __attribute__((ext_vector_type(8)));
typedef float f32x4  __attribute__((ext_vector_type(4)));
typedef float f32x2u __attribute__((ext_vector_type(2), aligned(4)));

__device__ __forceinline__ float bfl(unsigned d) { return __uint_as_float(d << 16); }
__device__ __forceinline__ float bfh(unsigned d) { return __uint_as_float(d & 0xffff0000u); }
__device__ __forceinline__ unsigned pk(float a, float b) {
    unsigned ua = (unsigned)__bfloat16_as_ushort(__float2bfloat16(a));
    unsigned ub = (unsigned)__bfloat16_as_ushort(__float2bfloat16(b));
    return ua | (ub << 16);
}

// A'[o][kk'] with kk' = (c>>5)*512 + k*32 + (c&31), value = w[o][c][15-k]
__global__ __launch_bounds__(256) void prep_weight(const float* __restrict__ w,
                                                   __hip_bfloat16* __restrict__ A) {
    int idx = blockIdx.x * 256 + threadIdx.x;      // o*2048 + kk'
    int o   = idx >> 11;
    int kkp = idx & 2047;
    int q   = kkp >> 9;
    int loc = kkp & 511;
    int k   = loc >> 5;
    int c   = (q << 5) + (loc & 31);
    A[idx]  = __float2bfloat16(w[(o << 11) + (c << 4) + (15 - k)]);
}

// inp8[b][g8][y][x][c8]: 16B word = 8 consecutive channels of one (y,x), bf16.
__global__ __launch_bounds__(256) void prep_input(const float* __restrict__ inp,
                                                  uint4* __restrict__ inp8) {
    int idx = blockIdx.x * 256 + threadIdx.x;      // (b*16+g8)*4096 + pos
    int bg  = idx >> 12;
    int pos = idx & 4095;
    const float* p = inp + (((size_t)bg << 3) << 12) + pos;  // channel g8*8, plane pos
    uint4 wd;
    wd.x = pk(p[0 << 12], p[1 << 12]);
    wd.y = pk(p[2 << 12], p[3 << 12]);
    wd.z = pk(p[4 << 12], p[5 << 12]);
    wd.w = pk(p[6 << 12], p[7 << 12]);
    inp8[idx] = wd;
}

// Block = 16 pixels of one (b,ho) row segment x 128 couts. 256 thr = (pix, tap).
// bf16 8-channel-interleaved LDS tile (double-buffered): one ds_read_b128 =
// one bilinear corner x 8 channels. Bs staged per 32-channel quarter with
// kk' = (c>>5)*512 + k*32 + (c&31) -> one ds_write_b128 per thread per group.
__global__ __launch_bounds__(256, 4) void deform_main(
        const float* __restrict__ inp, const uint4* __restrict__ inp8,
        const float* __restrict__ off, const float* __restrict__ msk,
        const __hip_bfloat16* __restrict__ A, const float* __restrict__ bias,
        float* __restrict__ out) {

    __shared__ __align__(16) __hip_bfloat16 Bs[16 * KKQ];   // 16 KB
    __shared__ __align__(16) uint4 tile[2][TILWDS];         // 16.9 KB

    const int t   = threadIdx.x;
    const int pix = t & 15;
    const int k   = t >> 4;            // tap 0..15

    // ---- block decode: bid&7 = batch (XCD/L2 pinning) ----
    const int bid = blockIdx.x;
    const int b   = bid & 7;
    const int g   = bid >> 3;
    const int ho  = g >> 2;
    const int wt  = (g & 3) << 4;
    const int wo  = wt + pix;
    const bool pvalid = (wo < WO);
    const int wo_c = pvalid ? wo : (WO - 1);
    const int r    = ho * WO + wo_c;

    // ---- window: 16 rows x 32 cols ----
    const int ry_lo = min(max(ho - 6, 0), H_ - 16);
    const int cx_lo = min(max(wt - 6, 0), W_ - 32) & ~3;

    // ---- per-(pixel,tap) sampling params ----
    const int ki = k >> 2, kj = k & 3;
    const size_t offb = (size_t)b * (2 * K_ * HW_);
    float dy = off[offb + (size_t)(2 * k)     * HW_ + r];
    float dx = off[offb + (size_t)(2 * k + 1) * HW_ + r];
    float mm = msk[(size_t)b * (K_ * HW_) + (size_t)k * HW_ + r];
    if (!pvalid) mm = 0.0f;

    float y   = dy + (float)(ki + ho);
    float x   = dx + (float)(kj + wo_c);
    float y0f = floorf(y), x0f = floorf(x);
    float wy  = y - y0f,   wx  = x - x0f;
    int y0 = (int)y0f, x0 = (int)x0f;
    int y1 = y0 + 1,   x1 = x0 + 1;

    float wy0v = (1.0f - wy) * ((y0 >= 0 && y0 < H_) ? mm : 0.0f);
    float wy1v = wy          * ((y1 >= 0 && y1 < H_) ? mm : 0.0f);
    int cy0 = min(max(y0, 0), H_ - 1), cy1 = min(max(y1, 0), H_ - 1);

    float wx0v = (1.0f - wx) * ((x0 >= 0 && x0 < W_) ? 1.0f : 0.0f);
    float wx1v = wx          * ((x1 >= 0 && x1 < W_) ? 1.0f : 0.0f);
    int xb = min(max(x0, 0), W_ - 2);
    int tsh = x0 - xb;
    float a0 = (tsh == 0) ? wx0v : ((tsh == -1) ? wx1v : 0.0f);
    float a1 = (tsh == 0) ? wx1v : ((tsh ==  1) ? wx0v : 0.0f);

    const float b00 = wy0v * a0, b01 = wy0v * a1;
    const float b10 = wy1v * a0, b11 = wy1v * a1;
    const int ad0 = cy0 * W_ + xb;     // exact global fallback addrs (f32 planar)
    const int ad1 = cy1 * W_ + xb;

    int t0 = cy0 - ry_lo, t1 = cy1 - ry_lo, u = xb - cx_lo;
    const bool intile = (t0 >= 0) & (t0 < 16) & (t1 >= 0) & (t1 < 16) &
                        (u >= 0) & (u <= 30);
    const float l00 = intile ? b00 : 0.0f, l01 = intile ? b01 : 0.0f;
    const float l10 = intile ? b10 : 0.0f, l11 = intile ? b11 : 0.0f;
    const int tc0 = min(max(t0, 0), 15) * TILW + min(max(u, 0), 30);
    const int tc1 = min(max(t1, 0), 15) * TILW + min(max(u, 0), 30);

    const float* pin  = inp  + (size_t)b * (CIN * H_ * W_);
    const uint4* pin8 = inp8 + ((size_t)b << 16);   // b*16*4096 words

    // ---- staging geometry: word (srow,scol) and (srow+8,scol) ----
    const int scol = t & 31;
    const int srow = t >> 5;
    int soff[2], lword[2];
    #pragma unroll
    for (int j = 0; j < 2; ++j) {
        int row  = srow + 8 * j;
        soff[j]  = (ry_lo + row) * W_ + cx_lo + scol;
        lword[j] = row * TILW + scol;
    }

    // MFMA identity
    const int lane = t & 63;
    const int wv   = t >> 6;
    const int quad = lane >> 4;
    const int mrow = lane & 15;        // == pix
    const int q8   = quad << 3;
    const __hip_bfloat16* Arow0 = A + ((size_t)(wv * 32 + mrow) << 11);
    const __hip_bfloat16* Arow1 = Arow0 + (16 << 11);
    const int brot = mrow << 3;

    f32x4 acc0 = {0.f, 0.f, 0.f, 0.f};
    f32x4 acc1 = {0.f, 0.f, 0.f, 0.f};

    // ---- prologue: group 0 -> tile[0]; prefetch group 1 ----
    uint4 pf[2];
    #pragma unroll
    for (int j = 0; j < 2; ++j) pf[j] = pin8[soff[j]];
    #pragma unroll
    for (int j = 0; j < 2; ++j) tile[0][lword[j]] = pf[j];
    #pragma unroll
    for (int j = 0; j < 2; ++j) pf[j] = pin8[(1 << 12) + soff[j]];
    __syncthreads();

    #pragma unroll 1
    for (int q = 0; q < 4; ++q) {
        #pragma unroll 1
        for (int gq = 0; gq < 4; ++gq) {
            const int gi  = (q << 2) + gq;         // current 8-ch group
            const int gn2 = (gi + 2) & 15;

            // write prefetched group gi+1 into other buffer; prefetch gi+2
            uint4* tw = tile[(gi + 1) & 1];
            #pragma unroll
            for (int j = 0; j < 2; ++j) tw[lword[j]] = pf[j];
            #pragma unroll
            for (int j = 0; j < 2; ++j) pf[j] = pin8[(gn2 << 12) + soff[j]];

            // gather: 4 corners x 8 channels from tile[gi&1]
            const uint4* tb = tile[gi & 1];
            uint4 c00 = tb[tc0], c01 = tb[tc0 + 1];
            uint4 c10 = tb[tc1], c11 = tb[tc1 + 1];
            float s[8];
            const unsigned* p00 = (const unsigned*)&c00;
            const unsigned* p01 = (const unsigned*)&c01;
            const unsigned* p10 = (const unsigned*)&c10;
            const unsigned* p11 = (const unsigned*)&c11;
            #pragma unroll
            for (int d = 0; d < 4; ++d) {
                s[2*d]   = l00*bfl(p00[d]) + l01*bfl(p01[d]) + l10*bfl(p10[d]) + l11*bfl(p11[d]);
                s[2*d+1] = l00*bfh(p00[d]) + l01*bfh(p01[d]) + l10*bfh(p10[d]) + l11*bfh(p11[d]);
            }
            if (!intile) {             // exec-skipped ~always; exact f32 tail
                #pragma unroll
                for (int c = 0; c < 8; ++c) {
                    const float* p = pin + ((size_t)((gi << 3) + c) << 12);
                    f32x2u h0 = *(const f32x2u*)(const void*)(p + ad0);
                    f32x2u h1 = *(const f32x2u*)(const void*)(p + ad1);
                    s[c] += b00 * h0[0] + b01 * h0[1] + b10 * h1[0] + b11 * h1[1];
                }
            }
            // one b128 Bs write: kk'_local = k*32 + gq*8 (+ pix*8 swizzle)
            uint4 wd;
            wd.x = pk(s[0], s[1]); wd.y = pk(s[2], s[3]);
            wd.z = pk(s[4], s[5]); wd.w = pk(s[6], s[7]);
            int bsi = (pix << 9) + (((k << 5) + (gq << 3) + (pix << 3)) & (KKQ - 1));
            *(uint4*)(void*)&Bs[bsi] = wd;
            __syncthreads();
        }

        // ---- MFMA over this quarter's 512 kk' ----
        const __hip_bfloat16* Aq0 = Arow0 + (q << 9);
        const __hip_bfloat16* Aq1 = Arow1 + (q << 9);
        const __hip_bfloat16* bsb = &Bs[mrow << 9];
        #pragma unroll 4
        for (int it = 0; it < 16; ++it) {
            int kk0 = (it << 5) + q8;
            bf16x8 av0 = *(const bf16x8*)(const void*)(Aq0 + kk0);
            bf16x8 av1 = *(const bf16x8*)(const void*)(Aq1 + kk0);
            bf16x8 bb  = *(const bf16x8*)(const void*)(bsb + ((kk0 + brot) & (KKQ - 1)));
            acc0 = __builtin_amdgcn_mfma_f32_16x16x32_bf16(av0, bb, acc0, 0, 0, 0);
            acc1 = __builtin_amdgcn_mfma_f32_16x16x32_bf16(av1, bb, acc1, 0, 0, 0);
        }
        __syncthreads();               // Bs reads done before next quarter's writes
    }

    // ---- epilogue ----
    if (pvalid) {
        size_t outb = (size_t)b * (COUT * HW_) + r;
        #pragma unroll
        for (int j = 0; j < 4; ++j) {
            int o = wv * 32 + quad * 4 + j;
            out[outb + (size_t)o        * HW_] = acc0[j] + bias[o];
            out[outb + (size_t)(o + 16) * HW_] = acc1[j] + bias[o + 16];
        }
    }
}

extern "C" void kernel_launch(void* const* d_in, const int* in_sizes, int n_in,
                              void* d_out, int out_size, void* d_ws, size_t ws_size,
                              hipStream_t stream) {
    const float* inp  = (const float*)d_in[0];
    const float* off  = (const float*)d_in[1];
    const float* msk  = (const float*)d_in[2];
    const float* wgt  = (const float*)d_in[3];
    const float* bias = (const float*)d_in[4];
    float* out = (float*)d_out;

    // d_ws layout: A' bf16 512 KB | inp8 bf16-interleaved 8.4 MB
    __hip_bfloat16* A = (__hip_bfloat16*)d_ws;
    uint4* inp8 = (uint4*)((char*)d_ws + (size_t)COUT * KKTOT * 2);

    prep_weight<<<(COUT * KKTOT) / 256, 256, 0, stream>>>(wgt, A);
    prep_input<<<(B_ * 16 * 4096) / 256, 256, 0, stream>>>(inp, inp8);

    int nblk = B_ * HO * 4;            // 1952 (bid&7 = batch)
    deform_main<<<nblk, 256, 0, stream>>>(inp, inp8, off, msk, A, bias, out);
}

// Round 9
// 221.850 us; speedup vs baseline: 1.1175x; 1.1175x over previous
//
#include <hip/hip_runtime.h>
#include <hip/hip_bf16.h>
#include <stdint.h>

// Problem constants
#define B_    8
#define CIN   128
#define H_    64
#define W_    64
#define COUT  128
#define K_    16
#define HO    61
#define WO    61
#define HW_   (HO * WO)          // 3721
#define KKTOT (CIN * K_)         // 2048
#define KKQ   512                // kk' per quarter (Bs = 16 KB)

typedef short bf16x8 __attribute__((ext_vector_type(8)));
typedef float f32x4  __attribute__((ext_vector_type(4)));

__device__ __forceinline__ float bfl(unsigned d) { return __uint_as_float(d << 16); }
__device__ __forceinline__ float bfh(unsigned d) { return __uint_as_float(d & 0xffff0000u); }
__device__ __forceinline__ unsigned pk(float a, float b) {
    unsigned ua = (unsigned)__bfloat16_as_ushort(__float2bfloat16(a));
    unsigned ub = (unsigned)__bfloat16_as_ushort(__float2bfloat16(b));
    return ua | (ub << 16);
}

// A'[o][kk'] with kk' = (c>>5)*512 + k*32 + (c&31), value = w[o][c][15-k]
__global__ __launch_bounds__(256) void prep_weight(const float* __restrict__ w,
                                                   __hip_bfloat16* __restrict__ A) {
    int idx = blockIdx.x * 256 + threadIdx.x;      // o*2048 + kk'
    int o   = idx >> 11;
    int kkp = idx & 2047;
    int q   = kkp >> 9;
    int loc = kkp & 511;
    int k   = loc >> 5;
    int c   = (q << 5) + (loc & 31);
    A[idx]  = __float2bfloat16(w[(o << 11) + (c << 4) + (15 - k)]);
}

// inp8[b][g8][y][x][c8]: 16B word = 8 consecutive channels of one (y,x), bf16.
__global__ __launch_bounds__(256) void prep_input(const float* __restrict__ inp,
                                                  uint4* __restrict__ inp8) {
    int idx = blockIdx.x * 256 + threadIdx.x;      // (b*16+g8)*4096 + pos
    int bg  = idx >> 12;
    int pos = idx & 4095;
    const float* p = inp + (((size_t)bg << 3) << 12) + pos;
    uint4 wd;
    wd.x = pk(p[0 << 12], p[1 << 12]);
    wd.y = pk(p[2 << 12], p[3 << 12]);
    wd.z = pk(p[4 << 12], p[5 << 12]);
    wd.w = pk(p[6 << 12], p[7 << 12]);
    inp8[idx] = wd;
}

// Block = 16 pixels of one (b,ho) row segment x 128 couts. 256 thr = (pix, tap).
// NO LDS tile: bilinear corners gathered directly from L2-resident inp8
// (4 x dwordx4 per 8-channel group, exact clamped+masked corner weights).
// Bs quarter (512 kk') -> MFMA. Only 8 barriers/block. LDS 16 KB.
__global__ __launch_bounds__(256, 6) void deform_main(
        const uint4* __restrict__ inp8,
        const float* __restrict__ off, const float* __restrict__ msk,
        const __hip_bfloat16* __restrict__ A, const float* __restrict__ bias,
        float* __restrict__ out) {

    __shared__ __align__(16) __hip_bfloat16 Bs[16 * KKQ];   // 16 KB

    const int t   = threadIdx.x;
    const int pix = t & 15;
    const int k   = t >> 4;            // tap 0..15

    // ---- block decode: bid&7 = batch (XCD/L2 pinning) ----
    const int bid = blockIdx.x;
    const int b   = bid & 7;
    const int g   = bid >> 3;
    const int ho  = g >> 2;
    const int wt  = (g & 3) << 4;
    const int wo  = wt + pix;
    const bool pvalid = (wo < WO);
    const int wo_c = pvalid ? wo : (WO - 1);
    const int r    = ho * WO + wo_c;

    // ---- per-(pixel,tap) sampling params (exact, unconditional) ----
    const int ki = k >> 2, kj = k & 3;
    const size_t offb = (size_t)b * (2 * K_ * HW_);
    float dy = off[offb + (size_t)(2 * k)     * HW_ + r];
    float dx = off[offb + (size_t)(2 * k + 1) * HW_ + r];
    float mm = msk[(size_t)b * (K_ * HW_) + (size_t)k * HW_ + r];
    if (!pvalid) mm = 0.0f;

    float y   = dy + (float)(ki + ho);
    float x   = dx + (float)(kj + wo_c);
    float y0f = floorf(y), x0f = floorf(x);
    float wy  = y - y0f,   wx  = x - x0f;
    int y0 = (int)y0f, x0 = (int)x0f;
    int y1 = y0 + 1,   x1 = x0 + 1;

    float vy0 = (y0 >= 0 && y0 < H_) ? 1.0f : 0.0f;
    float vy1 = (y1 >= 0 && y1 < H_) ? 1.0f : 0.0f;
    float vx0 = (x0 >= 0 && x0 < W_) ? 1.0f : 0.0f;
    float vx1 = (x1 >= 0 && x1 < W_) ? 1.0f : 0.0f;
    int cy0 = min(max(y0, 0), H_ - 1), cy1 = min(max(y1, 0), H_ - 1);
    int cx0 = min(max(x0, 0), W_ - 1), cx1 = min(max(x1, 0), W_ - 1);

    const float w00 = (1.0f - wy) * (1.0f - wx) * mm * vy0 * vx0;
    const float w01 = (1.0f - wy) * wx          * mm * vy0 * vx1;
    const float w10 = wy          * (1.0f - wx) * mm * vy1 * vx0;
    const float w11 = wy          * wx          * mm * vy1 * vx1;

    // corner word addresses within a channel-group plane (4096 words)
    const int ad00 = (cy0 << 6) + cx0, ad01 = (cy0 << 6) + cx1;
    const int ad10 = (cy1 << 6) + cx0, ad11 = (cy1 << 6) + cx1;

    const uint4* pin8 = inp8 + ((size_t)b << 16);   // batch base (16*4096 words)

    // MFMA identity
    const int lane = t & 63;
    const int wv   = t >> 6;
    const int quad = lane >> 4;
    const int mrow = lane & 15;        // == pix
    const int q8   = quad << 3;
    const __hip_bfloat16* Arow0 = A + ((size_t)(wv * 32 + mrow) << 11);
    const __hip_bfloat16* Arow1 = Arow0 + (16 << 11);
    const int brot = mrow << 3;

    f32x4 acc0 = {0.f, 0.f, 0.f, 0.f};
    f32x4 acc1 = {0.f, 0.f, 0.f, 0.f};

    #pragma unroll 1
    for (int q = 0; q < 4; ++q) {
        // ---- gather 4 x 8-channel groups straight from L2 ----
        #pragma unroll
        for (int gq = 0; gq < 4; ++gq) {
            const uint4* gb = pin8 + (((q << 2) + gq) << 12);
            uint4 c00 = gb[ad00], c01 = gb[ad01];
            uint4 c10 = gb[ad10], c11 = gb[ad11];
            const unsigned* p00 = (const unsigned*)&c00;
            const unsigned* p01 = (const unsigned*)&c01;
            const unsigned* p10 = (const unsigned*)&c10;
            const unsigned* p11 = (const unsigned*)&c11;
            float s[8];
            #pragma unroll
            for (int d = 0; d < 4; ++d) {
                s[2*d]   = w00*bfl(p00[d]) + w01*bfl(p01[d]) + w10*bfl(p10[d]) + w11*bfl(p11[d]);
                s[2*d+1] = w00*bfh(p00[d]) + w01*bfh(p01[d]) + w10*bfh(p10[d]) + w11*bfh(p11[d]);
            }
            uint4 wd;
            wd.x = pk(s[0], s[1]); wd.y = pk(s[2], s[3]);
            wd.z = pk(s[4], s[5]); wd.w = pk(s[6], s[7]);
            int bsi = (pix << 9) + (((k << 5) + (gq << 3) + (pix << 3)) & (KKQ - 1));
            *(uint4*)(void*)&Bs[bsi] = wd;
        }
        __syncthreads();               // Bs quarter complete

        // ---- MFMA over this quarter's 512 kk' ----
        const __hip_bfloat16* Aq0 = Arow0 + (q << 9);
        const __hip_bfloat16* Aq1 = Arow1 + (q << 9);
        const __hip_bfloat16* bsb = &Bs[mrow << 9];
        #pragma unroll 4
        for (int it = 0; it < 16; ++it) {
            int kk0 = (it << 5) + q8;
            bf16x8 av0 = *(const bf16x8*)(const void*)(Aq0 + kk0);
            bf16x8 av1 = *(const bf16x8*)(const void*)(Aq1 + kk0);
            bf16x8 bb  = *(const bf16x8*)(const void*)(bsb + ((kk0 + brot) & (KKQ - 1)));
            acc0 = __builtin_amdgcn_mfma_f32_16x16x32_bf16(av0, bb, acc0, 0, 0, 0);
            acc1 = __builtin_amdgcn_mfma_f32_16x16x32_bf16(av1, bb, acc1, 0, 0, 0);
        }
        __syncthreads();               // Bs reads done before next quarter's writes
    }

    // ---- epilogue: C/D col=lane&15 (pixel), row=quad*4+j (cout) ----
    if (pvalid) {
        size_t outb = (size_t)b * (COUT * HW_) + r;
        #pragma unroll
        for (int j = 0; j < 4; ++j) {
            int o = wv * 32 + quad * 4 + j;
            out[outb + (size_t)o        * HW_] = acc0[j] + bias[o];
            out[outb + (size_t)(o + 16) * HW_] = acc1[j] + bias[o + 16];
        }
    }
}

extern "C" void kernel_launch(void* const* d_in, const int* in_sizes, int n_in,
                              void* d_out, int out_size, void* d_ws, size_t ws_size,
                              hipStream_t stream) {
    const float* inp  = (const float*)d_in[0];
    const float* off  = (const float*)d_in[1];
    const float* msk  = (const float*)d_in[2];
    const float* wgt  = (const float*)d_in[3];
    const float* bias = (const float*)d_in[4];
    float* out = (float*)d_out;

    // d_ws layout: A' bf16 512 KB | inp8 bf16-interleaved 8.4 MB
    __hip_bfloat16* A = (__hip_bfloat16*)d_ws;
    uint4* inp8 = (uint4*)((char*)d_ws + (size_t)COUT * KKTOT * 2);

    prep_weight<<<(COUT * KKTOT) / 256, 256, 0, stream>>>(wgt, A);
    prep_input<<<(B_ * 16 * 4096) / 256, 256, 0, stream>>>(inp, inp8);

    int nblk = B_ * HO * 4;            // 1952 (bid&7 = batch)
    deform_main<<<nblk, 256, 0, stream>>>(inp8, off, msk, A, bias, out);
}

// Round 10
// 217.872 us; speedup vs baseline: 1.1379x; 1.0183x over previous
//
#include <hip/hip_runtime.h>
#include <hip/hip_bf16.h>
#include <stdint.h>

// Problem constants
#define B_    8
#define CIN   128
#define H_    64
#define W_    64
#define COUT  128
#define K_    16
#define HO    61
#define WO    61
#define HW_   (HO * WO)          // 3721
#define KKTOT (CIN * K_)         // 2048
#define KKQ   512                // kk' per quarter (Bs = 16 KB)

typedef short bf16x8 __attribute__((ext_vector_type(8)));
typedef float f32x4  __attribute__((ext_vector_type(4)));

__device__ __forceinline__ float bfl(unsigned d) { return __uint_as_float(d << 16); }
__device__ __forceinline__ float bfh(unsigned d) { return __uint_as_float(d & 0xffff0000u); }
__device__ __forceinline__ unsigned pk(float a, float b) {
    unsigned ua = (unsigned)__bfloat16_as_ushort(__float2bfloat16(a));
    unsigned ub = (unsigned)__bfloat16_as_ushort(__float2bfloat16(b));
    return ua | (ub << 16);
}

// LGKM-only barrier: LDS ops drained, in-flight global loads NOT drained.
// 0xc07f = vmcnt(max) expcnt(max) lgkmcnt(0).
__device__ __forceinline__ void lgkm_barrier() {
    __builtin_amdgcn_s_waitcnt(0xc07f);
    __builtin_amdgcn_s_barrier();
}

// A'[o][kk'] with kk' = (c>>5)*512 + k*32 + (c&31), value = w[o][c][15-k]
__global__ __launch_bounds__(256) void prep_weight(const float* __restrict__ w,
                                                   __hip_bfloat16* __restrict__ A) {
    int idx = blockIdx.x * 256 + threadIdx.x;      // o*2048 + kk'
    int o   = idx >> 11;
    int kkp = idx & 2047;
    int q   = kkp >> 9;
    int loc = kkp & 511;
    int k   = loc >> 5;
    int c   = (q << 5) + (loc & 31);
    A[idx]  = __float2bfloat16(w[(o << 11) + (c << 4) + (15 - k)]);
}

// inp8[b][g8][y][x][c8]: 16B word = 8 consecutive channels of one (y,x), bf16.
__global__ __launch_bounds__(256) void prep_input(const float* __restrict__ inp,
                                                  uint4* __restrict__ inp8) {
    int idx = blockIdx.x * 256 + threadIdx.x;      // (b*16+g8)*4096 + pos
    int bg  = idx >> 12;
    int pos = idx & 4095;
    const float* p = inp + (((size_t)bg << 3) << 12) + pos;
    uint4 wd;
    wd.x = pk(p[0 << 12], p[1 << 12]);
    wd.y = pk(p[2 << 12], p[3 << 12]);
    wd.z = pk(p[4 << 12], p[5 << 12]);
    wd.w = pk(p[6 << 12], p[7 << 12]);
    inp8[idx] = wd;
}

// Block = 16 pixels of one (b,ho) row segment x 128 couts. 256 thr = (pix, tap).
// Direct L2 gather (4 x dwordx4 per 8-ch group), software-pipelined one full
// quarter (16 loads) deep; LGKM-only barriers keep the prefetch alive across
// the Bs handoff. Bs quarter (512 kk') -> MFMA.
__global__ __launch_bounds__(256, 4) void deform_main(
        const uint4* __restrict__ inp8,
        const float* __restrict__ off, const float* __restrict__ msk,
        const __hip_bfloat16* __restrict__ A, const float* __restrict__ bias,
        float* __restrict__ out) {

    __shared__ __align__(16) __hip_bfloat16 Bs[16 * KKQ];   // 16 KB

    const int t   = threadIdx.x;
    const int pix = t & 15;
    const int k   = t >> 4;            // tap 0..15

    // ---- block decode: bid&7 = batch (XCD/L2 pinning) ----
    const int bid = blockIdx.x;
    const int b   = bid & 7;
    const int g   = bid >> 3;
    const int ho  = g >> 2;
    const int wt  = (g & 3) << 4;
    const int wo  = wt + pix;
    const bool pvalid = (wo < WO);
    const int wo_c = pvalid ? wo : (WO - 1);
    const int r    = ho * WO + wo_c;

    // ---- per-(pixel,tap) sampling params (exact, unconditional) ----
    const int ki = k >> 2, kj = k & 3;
    const size_t offb = (size_t)b * (2 * K_ * HW_);
    float dy = off[offb + (size_t)(2 * k)     * HW_ + r];
    float dx = off[offb + (size_t)(2 * k + 1) * HW_ + r];
    float mm = msk[(size_t)b * (K_ * HW_) + (size_t)k * HW_ + r];
    if (!pvalid) mm = 0.0f;

    float y   = dy + (float)(ki + ho);
    float x   = dx + (float)(kj + wo_c);
    float y0f = floorf(y), x0f = floorf(x);
    float wy  = y - y0f,   wx  = x - x0f;
    int y0 = (int)y0f, x0 = (int)x0f;
    int y1 = y0 + 1,   x1 = x0 + 1;

    float vy0 = (y0 >= 0 && y0 < H_) ? 1.0f : 0.0f;
    float vy1 = (y1 >= 0 && y1 < H_) ? 1.0f : 0.0f;
    float vx0 = (x0 >= 0 && x0 < W_) ? 1.0f : 0.0f;
    float vx1 = (x1 >= 0 && x1 < W_) ? 1.0f : 0.0f;
    int cy0 = min(max(y0, 0), H_ - 1), cy1 = min(max(y1, 0), H_ - 1);
    int cx0 = min(max(x0, 0), W_ - 1), cx1 = min(max(x1, 0), W_ - 1);

    const float w00 = (1.0f - wy) * (1.0f - wx) * mm * vy0 * vx0;
    const float w01 = (1.0f - wy) * wx          * mm * vy0 * vx1;
    const float w10 = wy          * (1.0f - wx) * mm * vy1 * vx0;
    const float w11 = wy          * wx          * mm * vy1 * vx1;

    // corner word addresses within a channel-group plane (4096 words)
    const int ad00 = (cy0 << 6) + cx0, ad01 = (cy0 << 6) + cx1;
    const int ad10 = (cy1 << 6) + cx0, ad11 = (cy1 << 6) + cx1;

    const uint4* pin8 = inp8 + ((size_t)b << 16);   // batch base (16*4096 words)

    // MFMA identity
    const int lane = t & 63;
    const int wv   = t >> 6;
    const int quad = lane >> 4;
    const int mrow = lane & 15;        // == pix
    const int q8   = quad << 3;
    const __hip_bfloat16* Arow0 = A + ((size_t)(wv * 32 + mrow) << 11);
    const __hip_bfloat16* Arow1 = Arow0 + (16 << 11);
    const int brot = mrow << 3;

    f32x4 acc0 = {0.f, 0.f, 0.f, 0.f};
    f32x4 acc1 = {0.f, 0.f, 0.f, 0.f};

    // ---- prologue: issue quarter 0's 16 gathers into pf ----
    uint4 pf[16];
    #pragma unroll
    for (int gq = 0; gq < 4; ++gq) {
        const uint4* gb = pin8 + (gq << 12);
        pf[gq * 4 + 0] = gb[ad00];
        pf[gq * 4 + 1] = gb[ad01];
        pf[gq * 4 + 2] = gb[ad10];
        pf[gq * 4 + 3] = gb[ad11];
    }

    #pragma unroll 1
    for (int q = 0; q < 4; ++q) {
        // ---- blend quarter q from prefetched regs -> Bs ----
        #pragma unroll
        for (int gq = 0; gq < 4; ++gq) {
            const unsigned* p00 = (const unsigned*)&pf[gq * 4 + 0];
            const unsigned* p01 = (const unsigned*)&pf[gq * 4 + 1];
            const unsigned* p10 = (const unsigned*)&pf[gq * 4 + 2];
            const unsigned* p11 = (const unsigned*)&pf[gq * 4 + 3];
            float s[8];
            #pragma unroll
            for (int d = 0; d < 4; ++d) {
                s[2*d]   = w00*bfl(p00[d]) + w01*bfl(p01[d]) + w10*bfl(p10[d]) + w11*bfl(p11[d]);
                s[2*d+1] = w00*bfh(p00[d]) + w01*bfh(p01[d]) + w10*bfh(p10[d]) + w11*bfh(p11[d]);
            }
            uint4 wd;
            wd.x = pk(s[0], s[1]); wd.y = pk(s[2], s[3]);
            wd.z = pk(s[4], s[5]); wd.w = pk(s[6], s[7]);
            int bsi = (pix << 9) + (((k << 5) + (gq << 3) + (pix << 3)) & (KKQ - 1));
            *(uint4*)(void*)&Bs[bsi] = wd;
        }

        // ---- issue quarter q+1's 16 gathers (reuse pf regs) ----
        if (q < 3) {
            #pragma unroll
            for (int gq = 0; gq < 4; ++gq) {
                const uint4* gb = pin8 + ((((q + 1) << 2) + gq) << 12);
                pf[gq * 4 + 0] = gb[ad00];
                pf[gq * 4 + 1] = gb[ad01];
                pf[gq * 4 + 2] = gb[ad10];
                pf[gq * 4 + 3] = gb[ad11];
            }
        }

        lgkm_barrier();                // Bs writes visible; gathers stay in flight

        // ---- MFMA over this quarter's 512 kk' ----
        const __hip_bfloat16* Aq0 = Arow0 + (q << 9);
        const __hip_bfloat16* Aq1 = Arow1 + (q << 9);
        const __hip_bfloat16* bsb = &Bs[mrow << 9];
        #pragma unroll 4
        for (int it = 0; it < 16; ++it) {
            int kk0 = (it << 5) + q8;
            bf16x8 av0 = *(const bf16x8*)(const void*)(Aq0 + kk0);
            bf16x8 av1 = *(const bf16x8*)(const void*)(Aq1 + kk0);
            bf16x8 bb  = *(const bf16x8*)(const void*)(bsb + ((kk0 + brot) & (KKQ - 1)));
            acc0 = __builtin_amdgcn_mfma_f32_16x16x32_bf16(av0, bb, acc0, 0, 0, 0);
            acc1 = __builtin_amdgcn_mfma_f32_16x16x32_bf16(av1, bb, acc1, 0, 0, 0);
        }

        lgkm_barrier();                // Bs reads done before next quarter's writes
    }

    // ---- epilogue: C/D col=lane&15 (pixel), row=quad*4+j (cout) ----
    if (pvalid) {
        size_t outb = (size_t)b * (COUT * HW_) + r;
        #pragma unroll
        for (int j = 0; j < 4; ++j) {
            int o = wv * 32 + quad * 4 + j;
            out[outb + (size_t)o        * HW_] = acc0[j] + bias[o];
            out[outb + (size_t)(o + 16) * HW_] = acc1[j] + bias[o + 16];
        }
    }
}

extern "C" void kernel_launch(void* const* d_in, const int* in_sizes, int n_in,
                              void* d_out, int out_size, void* d_ws, size_t ws_size,
                              hipStream_t stream) {
    const float* inp  = (const float*)d_in[0];
    const float* off  = (const float*)d_in[1];
    const float* msk  = (const float*)d_in[2];
    const float* wgt  = (const float*)d_in[3];
    const float* bias = (const float*)d_in[4];
    float* out = (float*)d_out;

    // d_ws layout: A' bf16 512 KB | inp8 bf16-interleaved 8.4 MB
    __hip_bfloat16* A = (__hip_bfloat16*)d_ws;
    uint4* inp8 = (uint4*)((char*)d_ws + (size_t)COUT * KKTOT * 2);

    prep_weight<<<(COUT * KKTOT) / 256, 256, 0, stream>>>(wgt, A);
    prep_input<<<(B_ * 16 * 4096) / 256, 256, 0, stream>>>(inp, inp8);

    int nblk = B_ * HO * 4;            // 1952 (bid&7 = batch)
    deform_main<<<nblk, 256, 0, stream>>>(inp8, off, msk, A, bias, out);
}